// Round 8
// baseline (170.376 us; speedup 1.0000x reference)
//
#include <hip/hip_runtime.h>

#define NN 100000
#define NE 1600000
#define D  128
#define EPS 1e-5f

#define GRID_G 782            // gemm tiles (128 rows each)
#define EPB   2047            // edges per edge-block; 782*2047 >= NE
#define NBLK  391             // ceil(NN/256)
#define MAXDEG 64

// ---- workspace layout (proven ws_size >= 52.9 MB in round 6) ----
#define OFF_CNT  0x0000000ULL       // u32[NN]        400 KB
#define OFF_DINV 0x0062000ULL       // f32[NN]        400 KB
#define OFF_CSR  0x00C4000ULL       // u32[NN*64]     25.6 MB
#define OFF_YB   0x1934000ULL       // bf16[NN*D]     25.6 MB
#define OFF_WSW  0x31A4000ULL       // bf16 swizzled W^T, 32 KB  (end ~52.1 MB)

typedef short short8 __attribute__((ext_vector_type(8)));
typedef float f32x4 __attribute__((ext_vector_type(4)));

union PK { uint4 u; short8 s; };

static __device__ __forceinline__ unsigned f2bf(float f) {
    unsigned u = __float_as_uint(f);
    return (u + 0x7fffu + ((u >> 16) & 1u)) >> 16;   // RNE, low 16 bits valid
}

// ---------------- prep: zero cnt + build swizzled bf16 W^T ----------------
__global__ void k_prep(const float* __restrict__ w, unsigned* __restrict__ cnt,
                       unsigned short* __restrict__ wsw) {
    int t = blockIdx.x * 256 + threadIdx.x;
    if (t < NN) cnt[t] = 0;
    if (t < 2048) {                       // tasks: n(128) x ko(16)
        int n = t & 127, ko = t >> 7;
        const float* wp = w + (size_t)(ko * 8) * D + n;
        uint4 pk;
        pk.x = f2bf(wp[0])     | (f2bf(wp[D])     << 16);
        pk.y = f2bf(wp[2 * D]) | (f2bf(wp[3 * D]) << 16);
        pk.z = f2bf(wp[4 * D]) | (f2bf(wp[5 * D]) << 16);
        pk.w = f2bf(wp[6 * D]) | (f2bf(wp[7 * D]) << 16);
        int idx = (n * 128 + ko * 8) ^ ((n & 7) << 3);
        *(uint4*)(&wsw[idx]) = pk;
    }
}

// ============ fused, block-specialized, LDS-FREE: even = edges, odd = GEMM ============
__launch_bounds__(256, 2)
__global__ void k_main(const float* __restrict__ x, const unsigned short* __restrict__ wsw,
                       const int* __restrict__ row, const int* __restrict__ col,
                       const float* __restrict__ adj,
                       unsigned* __restrict__ cnt, unsigned* __restrict__ csr,
                       unsigned short* __restrict__ yb) {
    int tid = threadIdx.x;
    int bid = blockIdx.x;

    if ((bid & 1) == 0) {
        // ---------------- edge path: count-atomic + direct padded-CSR scatter ----------------
        int eb = bid >> 1;
        int ebeg = eb * EPB;
        int eend = min(ebeg + EPB, NE);
        unsigned rk[8], ce[8];
        int er[8];
        #pragma unroll
        for (int j = 0; j < 8; ++j) {
            int e = ebeg + j * 256 + tid;
            er[j] = -1;
            if (e < eend) {
                int r = row[e];
                float a = adj[e];
                int aq = (int)rintf(a * 32767.0f);
                er[j] = r;
                ce[j] = (unsigned)col[e] | ((unsigned)aq << 17);
                rk[j] = atomicAdd(&cnt[r], 1u);        // rank (return needed)
            }
        }
        #pragma unroll
        for (int j = 0; j < 8; ++j) {
            if (er[j] >= 0 && rk[j] < MAXDEG)
                csr[(size_t)er[j] * MAXDEG + rk[j]] = ce[j];
        }
        return;
    }

    // ---------------- GEMM path: y = bf16(x) @ bf16(W), fragments straight from memory ----------------
    int base = (bid >> 1) * 128;
    int wv = tid >> 6, l = tid & 63;
    int lr = l & 15, g = l >> 4;

    f32x4 acc[2][8];
    #pragma unroll
    for (int ti = 0; ti < 2; ++ti)
        #pragma unroll
        for (int tj = 0; tj < 8; ++tj)
            acc[ti][tj] = (f32x4){0.f, 0.f, 0.f, 0.f};

    #pragma unroll
    for (int kc = 0; kc < 4; ++kc) {
        int kb = kc * 32 + g * 8;
        short8 a[2], b[8];
        #pragma unroll
        for (int ti = 0; ti < 2; ++ti) {
            int r0 = base + wv * 32 + ti * 16 + lr;
            float4 f0 = make_float4(0.f, 0.f, 0.f, 0.f), f1 = f0;
            if (r0 < NN) {
                const float* xp = x + (size_t)r0 * D + kb;
                f0 = *(const float4*)xp;
                f1 = *(const float4*)(xp + 4);
            }
            PK pk;
            pk.u.x = f2bf(f0.x) | (f2bf(f0.y) << 16);
            pk.u.y = f2bf(f0.z) | (f2bf(f0.w) << 16);
            pk.u.z = f2bf(f1.x) | (f2bf(f1.y) << 16);
            pk.u.w = f2bf(f1.z) | (f2bf(f1.w) << 16);
            a[ti] = pk.s;
        }
        #pragma unroll
        for (int tj = 0; tj < 8; ++tj) {
            int n0 = tj * 16 + lr;
            b[tj] = *(const short8*)(&wsw[(n0 * 128 + kb) ^ ((n0 & 7) << 3)]);
        }
        #pragma unroll
        for (int ti = 0; ti < 2; ++ti)
            #pragma unroll
            for (int tj = 0; tj < 8; ++tj)
                acc[ti][tj] = __builtin_amdgcn_mfma_f32_16x16x32_bf16(
                    a[ti], b[tj], acc[ti][tj], 0, 0, 0);
    }

    #pragma unroll
    for (int ti = 0; ti < 2; ++ti) {
        #pragma unroll
        for (int reg = 0; reg < 4; ++reg) {
            int gr = base + wv * 32 + ti * 16 + g * 4 + reg;
            if (gr < NN) {
                #pragma unroll
                for (int tj = 0; tj < 8; ++tj)
                    yb[(size_t)gr * D + tj * 16 + lr] = (unsigned short)f2bf(acc[ti][tj][reg]);
            }
        }
    }
}

// ---------------- dinv: exact integer degree from padded CSR ----------------
__global__ void k_dinv(const unsigned* __restrict__ cnt, const unsigned* __restrict__ csr,
                       float* __restrict__ dinv) {
    int i = blockIdx.x * 256 + threadIdx.x;
    if (i >= NN) return;
    int c = min((int)cnt[i], MAXDEG);
    const uint4* p = (const uint4*)(csr + (size_t)i * MAXDEG);
    int s = 0;
    #pragma unroll
    for (int q = 0; q < 16; ++q) {
        uint4 v = p[q];
        int b = q * 4;
        if (b + 0 < c) s += (int)(v.x >> 17);
        if (b + 1 < c) s += (int)(v.y >> 17);
        if (b + 2 < c) s += (int)(v.z >> 17);
        if (b + 3 < c) s += (int)(v.w >> 17);
    }
    float d = (float)s * (1.0f / 32767.0f);
    d = (d == 0.0f) ? EPS : d;
    dinv[i] = rsqrtf(d + EPS);
}

// ---------------- per-row aggregation: 1 row per 16-lane quarter-wave ----------------
__launch_bounds__(256, 4)
__global__ void k_rows(const unsigned* __restrict__ cnt, const float* __restrict__ dinv,
                       const unsigned* __restrict__ csr,
                       const unsigned short* __restrict__ yb,
                       const float* __restrict__ bias, float* __restrict__ out) {
    int gt  = blockIdx.x * blockDim.x + threadIdx.x;
    int wid = gt >> 4;              // quarter-wave id = row
    int lq  = gt & 15;              // lane in quarter: cols 8lq..8lq+7
    if (wid >= NN) return;

    int c = min((int)cnt[wid], MAXDEG);
    const unsigned* cp = csr + (size_t)wid * MAXDEG;

    float a0 = 0.f, a1 = 0.f, a2 = 0.f, a3 = 0.f;
    float a4 = 0.f, a5 = 0.f, a6 = 0.f, a7 = 0.f;

    for (int j = 0; j < c; j += 8) {
        uint4 q0 = *(const uint4*)(cp + j);        // padded region: always in-bounds
        uint4 q1 = *(const uint4*)(cp + j + 4);
        unsigned ee[8] = {q0.x, q0.y, q0.z, q0.w, q1.x, q1.y, q1.z, q1.w};
        uint4 yq[8];
        float wv[8];
        int cm[8];
        #pragma unroll
        for (int t = 0; t < 8; ++t) cm[t] = min((int)(ee[t] & 0x1FFFFu), NN - 1);
        #pragma unroll
        for (int t = 0; t < 8; ++t)
            yq[t] = *((const uint4*)(yb + (size_t)cm[t] * D) + lq);
        #pragma unroll
        for (int t = 0; t < 8; ++t)
            wv[t] = (j + t < c) ? (float)(ee[t] >> 17) * dinv[cm[t]] : 0.f;
        #pragma unroll
        for (int t = 0; t < 8; ++t) {
            a0 += wv[t] * __uint_as_float(yq[t].x << 16);
            a1 += wv[t] * __uint_as_float(yq[t].x & 0xffff0000u);
            a2 += wv[t] * __uint_as_float(yq[t].y << 16);
            a3 += wv[t] * __uint_as_float(yq[t].y & 0xffff0000u);
            a4 += wv[t] * __uint_as_float(yq[t].z << 16);
            a5 += wv[t] * __uint_as_float(yq[t].z & 0xffff0000u);
            a6 += wv[t] * __uint_as_float(yq[t].w << 16);
            a7 += wv[t] * __uint_as_float(yq[t].w & 0xffff0000u);
        }
    }

    float scale = dinv[wid] * (1.0f / 32767.0f);
    const float4* bp = (const float4*)bias;
    float4 b0 = bp[lq * 2], b1 = bp[lq * 2 + 1];
    float4 r0 = make_float4(a0 * scale + b0.x, a1 * scale + b0.y,
                            a2 * scale + b0.z, a3 * scale + b0.w);
    float4 r1 = make_float4(a4 * scale + b1.x, a5 * scale + b1.y,
                            a6 * scale + b1.z, a7 * scale + b1.w);
    float4* op = (float4*)(out + (size_t)wid * D) + lq * 2;
    op[0] = r0;
    op[1] = r1;
}

extern "C" void kernel_launch(void* const* d_in, const int* in_sizes, int n_in,
                              void* d_out, int out_size, void* d_ws, size_t ws_size,
                              hipStream_t stream) {
    const float* x    = (const float*)d_in[0];
    const int*   row  = (const int*)d_in[1];
    const int*   col  = (const int*)d_in[2];
    const float* adj  = (const float*)d_in[3];
    const float* wgt  = (const float*)d_in[4];
    const float* bias = (const float*)d_in[5];
    float* out = (float*)d_out;
    char*  ws  = (char*)d_ws;

    unsigned* cnt  = (unsigned*)(ws + OFF_CNT);
    float*    dinv = (float*)(ws + OFF_DINV);
    unsigned* csr  = (unsigned*)(ws + OFF_CSR);
    unsigned short* yb  = (unsigned short*)(ws + OFF_YB);
    unsigned short* wsw = (unsigned short*)(ws + OFF_WSW);

    k_prep<<<NBLK, 256, 0, stream>>>(wgt, cnt, wsw);
    k_main<<<2 * GRID_G, 256, 0, stream>>>(x, wsw, row, col, adj, cnt, csr, yb);
    k_dinv<<<NBLK, 256, 0, stream>>>(cnt, csr, dinv);
    k_rows<<<(NN * 16 + 255) / 256, 256, 0, stream>>>(cnt, dinv, csr, yb, bias, out);
}